// Round 6
// baseline (456.602 us; speedup 1.0000x reference)
//
#include <hip/hip_runtime.h>
#include <math.h>

#define N_NODES 40000
#define M_PAD   40064      // 313 * 128
#define N_EDGES 640000
#define D       256
#define H       8
#define DFF     1024
#define D3      768
#define ATT_SCALE 0.0625f  // 256^-0.5
#define LN_EPS  1e-5f

typedef __attribute__((ext_vector_type(8))) short short8;
typedef __attribute__((ext_vector_type(4))) float f32x4;
typedef __attribute__((ext_vector_type(2))) float f32x2;

__device__ __forceinline__ unsigned short f2bf(float f) {
    unsigned int u = __builtin_bit_cast(unsigned int, f);
    u = (u + 0x7FFF + ((u >> 16) & 1)) >> 16;   // RTNE
    return (unsigned short)u;
}
__device__ __forceinline__ float bf2f(unsigned short u) {
    return __builtin_bit_cast(float, (unsigned int)u << 16);
}

// Fast exact-gelu: Abramowitz-Stegun 7.1.26 erf (|eps| <= 1.5e-7, branchless).
__device__ __forceinline__ float fast_gelu(float x) {
    const float z  = fabsf(x) * 0.70710678118654752f;
    const float t  = __builtin_amdgcn_rcpf(1.0f + 0.3275911f * z);
    float p = 1.061405429f;
    p = p * t - 1.453152027f;
    p = p * t + 1.421413741f;
    p = p * t - 0.284496736f;
    p = p * t + 0.254829592f;
    const float e  = __expf(-z * z);
    const float ea = 1.0f - p * t * e;          // erf(|x|/sqrt2)
    const float er = (x < 0.0f) ? -ea : ea;
    return 0.5f * x * (1.0f + er);
}

#define GLOAD_LDS16(g, l) \
    __builtin_amdgcn_global_load_lds((const __attribute__((address_space(1))) void*)(g), \
                                     (__attribute__((address_space(3))) void*)(l), 16, 0, 0)

// ---------------- fp8 e4m3 pack/unpack (HW cvt on gfx950, SW fallback) -----
#if __has_builtin(__builtin_amdgcn_cvt_pk_fp8_f32) && __has_builtin(__builtin_amdgcn_cvt_pk_f32_fp8)
#define HW_FP8 1
#else
#define HW_FP8 0
__device__ __forceinline__ unsigned char enc_e4m3(float f) {
    unsigned int u = __builtin_bit_cast(unsigned int, f);
    unsigned int s = (u >> 24) & 0x80;
    float a = fabsf(f);
    if (a >= 0x1p-6f) {
        unsigned int bits = __builtin_bit_cast(unsigned int, a);
        unsigned int q = bits >> 20;
        unsigned int rem = bits & 0xFFFFFu;
        q += (rem > 0x80000u) || ((rem == 0x80000u) && (q & 1));
        q -= 960;                          // rebias (120<<3)
        if (q > 126) q = 126;              // clamp to 448
        return (unsigned char)(s | q);
    }
    float t = a * 512.0f;
    unsigned int r = (unsigned int)rintf(t);   // RNE; 8 -> min normal naturally
    return (unsigned char)(s | r);
}
__device__ __forceinline__ float dec_e4m3(unsigned int v) {
    unsigned int em = v & 0x7f;
    float n = __builtin_bit_cast(float, (em << 20) + 0x3C000000u);
    float r = (em >= 8) ? n : (float)em * 0x1p-9f;
    return (v & 0x80) ? -r : r;
}
#endif

__device__ __forceinline__ unsigned int pack4_e4m3(float a, float b, float c, float d) {
#if HW_FP8
    unsigned int w = (unsigned int)__builtin_amdgcn_cvt_pk_fp8_f32(a, b, 0, false);
    w = (unsigned int)__builtin_amdgcn_cvt_pk_fp8_f32(c, d, (int)w, true);
    return w;
#else
    return (unsigned int)enc_e4m3(a) | ((unsigned int)enc_e4m3(b) << 8)
         | ((unsigned int)enc_e4m3(c) << 16) | ((unsigned int)enc_e4m3(d) << 24);
#endif
}
__device__ __forceinline__ void dec4_e4m3(unsigned int w, float& a, float& b, float& c, float& d) {
#if HW_FP8
    f32x2 lo = __builtin_amdgcn_cvt_pk_f32_fp8((int)w, false);
    f32x2 hi = __builtin_amdgcn_cvt_pk_f32_fp8((int)w, true);
    a = lo[0]; b = lo[1]; c = hi[0]; d = hi[1];
#else
    a = dec_e4m3(w & 0xff); b = dec_e4m3((w >> 8) & 0xff);
    c = dec_e4m3((w >> 16) & 0xff); d = dec_e4m3(w >> 24);
#endif
}

// ---------------------------------------------------------------------------
// LayerNorm -> bf16 output in MFMA A-fragment order [M/16][D/8][16][8].
// Covers pad rows [N_NODES, M_PAD) with zeros (replaces a memset).
// ---------------------------------------------------------------------------
__global__ __launch_bounds__(256) void ln_bf_kernel(const float* __restrict__ in,
                                                    const float* __restrict__ g,
                                                    const float* __restrict__ b,
                                                    unsigned short* __restrict__ out)
{
    const int row  = blockIdx.x * 4 + (threadIdx.x >> 6);
    const int lane = threadIdx.x & 63;
    const size_t off = (((size_t)(row >> 4) * (D / 8) + (lane >> 1)) * 16 + (row & 15)) * 8
                       + (lane & 1) * 4;
    if (row >= N_NODES) {
        ushort4 z = {0, 0, 0, 0};
        *reinterpret_cast<ushort4*>(out + off) = z;
        return;
    }
    const float4 v = *reinterpret_cast<const float4*>(in + (size_t)row * D + lane * 4);
    float s  = v.x + v.y + v.z + v.w;
    float s2 = v.x * v.x + v.y * v.y + v.z * v.z + v.w * v.w;
#pragma unroll
    for (int o = 32; o > 0; o >>= 1) {
        s  += __shfl_xor(s,  o, 64);
        s2 += __shfl_xor(s2, o, 64);
    }
    const float mu  = s * (1.0f / D);
    const float var = s2 * (1.0f / D) - mu * mu;
    const float rs  = rsqrtf(var + LN_EPS);
    const float4 gg = *reinterpret_cast<const float4*>(g + lane * 4);
    const float4 bb = *reinterpret_cast<const float4*>(b + lane * 4);
    ushort4 o4;
    o4.x = f2bf((v.x - mu) * rs * gg.x + bb.x);
    o4.y = f2bf((v.y - mu) * rs * gg.y + bb.y);
    o4.z = f2bf((v.z - mu) * rs * gg.z + bb.z);
    o4.w = f2bf((v.w - mu) * rs * gg.w + bb.w);
    *reinterpret_cast<ushort4*>(out + off) = o4;
}

// ---------------------------------------------------------------------------
// Weight pack: W[K][N] fp32 -> bf16 packed [N/16][K/8][16][8]. All three
// weights in ONE kernel (one launch).
// ---------------------------------------------------------------------------
template <int K, int N>
__device__ __forceinline__ void pack_body(const float* __restrict__ W,
                                          unsigned short* __restrict__ Wpk, int blk)
{
    const int idx = blk * 256 + threadIdx.x;   // [N/16][K/8][16]
    const int ni  = idx & 15;
    const int kc  = (idx >> 4) % (K / 8);
    const int nt  = idx / (16 * (K / 8));
    const int n   = nt * 16 + ni;
    unsigned short o[8];
#pragma unroll
    for (int i = 0; i < 8; ++i)
        o[i] = f2bf(W[(size_t)(kc * 8 + i) * N + n]);
    *reinterpret_cast<short8*>(Wpk + (size_t)idx * 8) = *reinterpret_cast<short8*>(o);
}

__global__ __launch_bounds__(256) void pack_all_kernel(const float* __restrict__ Wqkv,
                                                       const float* __restrict__ W_in,
                                                       const float* __restrict__ W_out,
                                                       unsigned short* __restrict__ pq,
                                                       unsigned short* __restrict__ pi,
                                                       unsigned short* __restrict__ po)
{
    const int b = blockIdx.x;
    if (b < 96)       pack_body<D, D3 >(Wqkv, pq, b);
    else if (b < 224) pack_body<D, DFF>(W_in, pi, b - 96);
    else              pack_body<DFF, D>(W_out, po, b - 224);
}

// ---------------------------------------------------------------------------
// bf16 MFMA GEMM -- 2-phase double-buffered staging pipeline (T3/T4):
// issue next tile's global_load_lds BEFORE computing current tile, then
// s_waitcnt vmcnt(4) (current tile's loads done, next tile's stay in
// flight ACROSS the barrier) + raw s_barrier. Removes the vmcnt(0) drain
// that exposed full HBM latency on every K-step (the short-K killer).
// 128x128 tile, 4 waves, BK=32, LDS 2x16=32 KB, 4 blocks/CU.
// Panel-colocating XCD swizzle. MFMA operands SWAPPED: D maps to row
// r = lane&15, cols n = (lane>>4)*4+t -> 4 consecutive cols per thread.
// EPI 0: qkv split -> q (cols<256) unscaled fp8 e4m3, k|v bf16 row-major
// EPI 1: bf16 C in fragment order [M/16][N/8][16][8] + fast exact gelu
// EPI 2: fp32 C row-major += Xadd, nontemporal f32x4 load/store
// ---------------------------------------------------------------------------
template <int EPI, int K, int N>
__global__ __launch_bounds__(256, 4) void mfma_gemm_kernel(const unsigned short* __restrict__ A,
                                                           const unsigned short* __restrict__ Bpk,
                                                           const float* __restrict__ bias,
                                                           void* __restrict__ Cout,
                                                           void* __restrict__ Cout2,
                                                           const float* __restrict__ Xadd)
{
    constexpr int C  = N / 128;          // col tiles
    constexpr int P  = M_PAD / 128;      // 313 row panels
    constexpr int NT = K / 32;           // K-steps (8 or 32)

    const int bid = blockIdx.x;
    const int xcd = bid & 7;
    const int tt  = bid >> 3;
    const int c   = tt % C;
    const int p   = (tt / C) * 8 + xcd;
    if (p >= P) return;

    __shared__ unsigned short As[2][4096];   // [buf][mt8][16][8] = 2 x 8 KB
    __shared__ unsigned short Bs[2][4096];

    const int tid  = threadIdx.x;
    const int wave = tid >> 6;
    const int lane = tid & 63;
    const int row0 = p * 128;
    const int col0 = c * 128;
    const int wm   = (wave >> 1) * 64;
    const int wn   = (wave & 1) * 64;
    const int g    = lane >> 4;
    const int q    = lane & 15;

    f32x4 acc[4][4] = {};

    const int fragoff = g * 128 + q * 8;
    const int mt0 = wave * 2;

    // Per-wave staging: 2 A-chunks + 2 B-chunks of 1 KB (64 lanes x 16 B).
    auto STAGE = [&](int t, int pb) {
        const int kq = t * 4;   // k-chunk index (K/8 units)
#pragma unroll
        for (int cc = 0; cc < 2; ++cc) {
            const int mt = mt0 + cc;                 // 0..7
            const unsigned short* gA =
                A + ((size_t)(row0 / 16 + mt) * (K / 8) + kq) * 128 + lane * 8;
            GLOAD_LDS16(gA, &As[pb][mt * 512]);
            const unsigned short* gB =
                Bpk + ((size_t)(col0 / 16 + mt) * (K / 8) + kq) * 128 + lane * 8;
            GLOAD_LDS16(gB, &Bs[pb][mt * 512]);
        }
    };

    STAGE(0, 0);
#pragma unroll 1
    for (int t = 0; t < NT; ++t) {
        const int cur = t & 1;
        if (t + 1 < NT) {
            STAGE(t + 1, cur ^ 1);                       // prefetch stays in flight
            asm volatile("s_waitcnt vmcnt(4)" ::: "memory");   // cur's 4 loads landed
        } else {
            asm volatile("s_waitcnt vmcnt(0)" ::: "memory");
        }
        __builtin_amdgcn_s_barrier();                    // cur visible to all waves

        short8 af[4], bf[4];
#pragma unroll
        for (int i = 0; i < 4; ++i) {
            af[i] = *reinterpret_cast<const short8*>(&As[cur][(wm / 16 + i) * 512 + fragoff]);
            bf[i] = *reinterpret_cast<const short8*>(&Bs[cur][(wn / 16 + i) * 512 + fragoff]);
        }
#pragma unroll
        for (int i = 0; i < 4; ++i)
#pragma unroll
            for (int j = 0; j < 4; ++j)
                acc[i][j] = __builtin_amdgcn_mfma_f32_16x16x32_bf16(bf[j], af[i], acc[i][j], 0, 0, 0);

        if (t + 1 < NT) __builtin_amdgcn_s_barrier();    // cur reads done -> t+1 may overwrite
    }

    // Swapped D layout: r = row0+wm+i*16+q ; n = col0+wn+j*16+g*4+t (t=0..3)
    if constexpr (EPI == 0) {
        if (col0 < 256) {   // q columns -> fp8, UNSCALED (scale folded into k at attn)
            unsigned char* q8 = (unsigned char*)Cout;
#pragma unroll
            for (int j = 0; j < 4; ++j) {
                const int nb = col0 + wn + j * 16 + g * 4;
                const float4 bz = *reinterpret_cast<const float4*>(bias + nb);
#pragma unroll
                for (int i = 0; i < 4; ++i) {
                    const int r = row0 + wm + i * 16 + q;
                    if (r >= N_NODES) continue;
                    const unsigned int w = pack4_e4m3(acc[i][j][0] + bz.x, acc[i][j][1] + bz.y,
                                                      acc[i][j][2] + bz.z, acc[i][j][3] + bz.w);
                    *reinterpret_cast<unsigned int*>(q8 + (size_t)r * 256 + nb) = w;
                }
            }
        } else {            // k|v columns -> bf16 row-major [node][512]
            unsigned short* kv = (unsigned short*)Cout2;
#pragma unroll
            for (int j = 0; j < 4; ++j) {
                const int nb = col0 + wn + j * 16 + g * 4;
                const float4 bz = *reinterpret_cast<const float4*>(bias + nb);
#pragma unroll
                for (int i = 0; i < 4; ++i) {
                    const int r = row0 + wm + i * 16 + q;
                    if (r >= N_NODES) continue;
                    ushort4 u;
                    u.x = f2bf(acc[i][j][0] + bz.x);
                    u.y = f2bf(acc[i][j][1] + bz.y);
                    u.z = f2bf(acc[i][j][2] + bz.z);
                    u.w = f2bf(acc[i][j][3] + bz.w);
                    *reinterpret_cast<ushort4*>(kv + (size_t)r * 512 + (nb - 256)) = u;
                }
            }
        }
    } else if constexpr (EPI == 1) {
#pragma unroll
        for (int j = 0; j < 4; ++j) {
            const int nb = col0 + wn + j * 16 + g * 4;
            const float4 bz = *reinterpret_cast<const float4*>(bias + nb);
#pragma unroll
            for (int i = 0; i < 4; ++i) {
                const int r = row0 + wm + i * 16 + q;   // pad rows stored too (finite)
                const float o0 = fast_gelu(acc[i][j][0] + bz.x);
                const float o1 = fast_gelu(acc[i][j][1] + bz.y);
                const float o2 = fast_gelu(acc[i][j][2] + bz.z);
                const float o3 = fast_gelu(acc[i][j][3] + bz.w);
                const size_t off = (((size_t)(r >> 4) * (N / 8) + (nb >> 3)) * 16
                                    + (r & 15)) * 8 + (nb & 7);
                ushort4 u;
                u.x = f2bf(o0); u.y = f2bf(o1); u.z = f2bf(o2); u.w = f2bf(o3);
                *reinterpret_cast<ushort4*>((unsigned short*)Cout + off) = u;
            }
        }
    } else {
#pragma unroll
        for (int j = 0; j < 4; ++j) {
            const int nb = col0 + wn + j * 16 + g * 4;
            const float4 bz = *reinterpret_cast<const float4*>(bias + nb);
#pragma unroll
            for (int i = 0; i < 4; ++i) {
                const int r = row0 + wm + i * 16 + q;
                if (r >= N_NODES) continue;
                const f32x4 xd = __builtin_nontemporal_load(
                    reinterpret_cast<const f32x4*>(Xadd + (size_t)r * N + nb));
                f32x4 ov;
                ov[0] = acc[i][j][0] + bz.x + xd[0];
                ov[1] = acc[i][j][1] + bz.y + xd[1];
                ov[2] = acc[i][j][2] + bz.z + xd[2];
                ov[3] = acc[i][j][3] + bz.w + xd[3];
                __builtin_nontemporal_store(ov,
                    reinterpret_cast<f32x4*>((float*)Cout + (size_t)r * N + nb));
            }
        }
    }
}

// ---------------------------------------------------------------------------
// CSR build
// ---------------------------------------------------------------------------
__global__ __launch_bounds__(256) void hist_kernel(const int* __restrict__ dst,
                                                   int* __restrict__ counts)
{
    const int i = blockIdx.x * 256 + threadIdx.x;
    atomicAdd(&counts[dst[i]], 1);
}

__global__ __launch_bounds__(1024) void scan_kernel(const int* __restrict__ counts,
                                                    int* __restrict__ rowptr,
                                                    int* __restrict__ cursor)
{
    const int PER = 40;
    const int tid  = threadIdx.x;
    const int base = tid * PER;
    int c[PER];
    int s = 0;
#pragma unroll
    for (int i = 0; i < PER; ++i) {
        const int idx = base + i;
        c[i] = (idx < N_NODES) ? counts[idx] : 0;
        s += c[i];
    }
    __shared__ int sm[1024];
    sm[tid] = s;
    __syncthreads();
    for (int off = 1; off < 1024; off <<= 1) {
        int t = (tid >= off) ? sm[tid - off] : 0;
        __syncthreads();
        sm[tid] += t;
        __syncthreads();
    }
    int run = sm[tid] - s;
#pragma unroll
    for (int i = 0; i < PER; ++i) {
        const int idx = base + i;
        if (idx < N_NODES) {
            rowptr[idx] = run;
            cursor[idx] = run;
            run += c[i];
        }
    }
    if (tid == 1023) rowptr[N_NODES] = sm[1023];
}

__global__ __launch_bounds__(256) void fill_kernel(const int* __restrict__ src,
                                                   const int* __restrict__ dst,
                                                   int* __restrict__ cursor,
                                                   int* __restrict__ srcs)
{
    const int e = blockIdx.x * 256 + threadIdx.x;
    const int pos = atomicAdd(&cursor[dst[e]], 1);
    if (pos >= 0 && pos < N_EDGES) srcs[pos] = src[e];
}

// ---------------------------------------------------------------------------
// Fused attention: q fp8 (256 B/row) + k|v bf16 (1024 B/row, pow2 stride).
// One wave per dst node; src list coalesce-prefetched, readlane broadcast,
// 4-edge unroll. k scaled by ATT_SCALE at load (q stored unscaled).
// Outputs: x fp32 row-major, xn bf16 in fragment order.
// ---------------------------------------------------------------------------
__global__ __launch_bounds__(256) void fused_attn_kernel(const unsigned char* __restrict__ qf8,
                                                         const unsigned short* __restrict__ kv,
                                                         const int* __restrict__ srcs,
                                                         const int* __restrict__ rowptr,
                                                         const float* __restrict__ triplet_h,
                                                         const float* __restrict__ g,
                                                         const float* __restrict__ b,
                                                         float* __restrict__ x,
                                                         unsigned short* __restrict__ xn)
{
    const int node = blockIdx.x * 4 + (threadIdx.x >> 6);
    const int lane = threadIdx.x & 63;
    int beg = rowptr[node];
    int end = rowptr[node + 1];
    beg = max(0, min(beg, N_EDGES));
    end = max(beg, min(end, N_EDGES));
    const int deg = end - beg;

    const ushort4 ku = *reinterpret_cast<const ushort4*>(
        kv + (size_t)node * 512 + lane * 4);
    const float k0 = bf2f(ku.x) * ATT_SCALE, k1 = bf2f(ku.y) * ATT_SCALE;
    const float k2 = bf2f(ku.z) * ATT_SCALE, k3 = bf2f(ku.w) * ATT_SCALE;

    float dsum = 0.0f;
    float4 acc = {0.0f, 0.0f, 0.0f, 0.0f};

    for (int base = 0; base < deg; base += 64) {
        const int cnt = min(64, deg - base);
        const int idx = base + lane;
        const int sv = (idx < deg) ? srcs[beg + idx] : 0;   // coalesced prefetch
        int j = 0;
        for (; j + 4 <= cnt; j += 4) {
            const int s0 = __builtin_amdgcn_readlane(sv, j);
            const int s1 = __builtin_amdgcn_readlane(sv, j + 1);
            const int s2 = __builtin_amdgcn_readlane(sv, j + 2);
            const int s3 = __builtin_amdgcn_readlane(sv, j + 3);
            const unsigned int qa = *reinterpret_cast<const unsigned int*>(qf8 + (size_t)s0 * 256 + lane * 4);
            const unsigned int qb = *reinterpret_cast<const unsigned int*>(qf8 + (size_t)s1 * 256 + lane * 4);
            const unsigned int qc = *reinterpret_cast<const unsigned int*>(qf8 + (size_t)s2 * 256 + lane * 4);
            const unsigned int qd = *reinterpret_cast<const unsigned int*>(qf8 + (size_t)s3 * 256 + lane * 4);
            const ushort4 va = *reinterpret_cast<const ushort4*>(kv + (size_t)s0 * 512 + 256 + lane * 4);
            const ushort4 vb = *reinterpret_cast<const ushort4*>(kv + (size_t)s1 * 512 + 256 + lane * 4);
            const ushort4 vc = *reinterpret_cast<const ushort4*>(kv + (size_t)s2 * 512 + 256 + lane * 4);
            const ushort4 vd = *reinterpret_cast<const ushort4*>(kv + (size_t)s3 * 512 + 256 + lane * 4);
            float a0, a1, a2, a3;
            dec4_e4m3(qa, a0, a1, a2, a3);
            float p0 = a0 * k0 + a1 * k1 + a2 * k2 + a3 * k3;
            dec4_e4m3(qb, a0, a1, a2, a3);
            float p1 = a0 * k0 + a1 * k1 + a2 * k2 + a3 * k3;
            dec4_e4m3(qc, a0, a1, a2, a3);
            float p2 = a0 * k0 + a1 * k1 + a2 * k2 + a3 * k3;
            dec4_e4m3(qd, a0, a1, a2, a3);
            float p3 = a0 * k0 + a1 * k1 + a2 * k2 + a3 * k3;
            p0 += __shfl_xor(p0, 1, 64); p1 += __shfl_xor(p1, 1, 64);
            p2 += __shfl_xor(p2, 1, 64); p3 += __shfl_xor(p3, 1, 64);
            p0 += __shfl_xor(p0, 2, 64); p1 += __shfl_xor(p1, 2, 64);
            p2 += __shfl_xor(p2, 2, 64); p3 += __shfl_xor(p3, 2, 64);
            p0 += __shfl_xor(p0, 4, 64); p1 += __shfl_xor(p1, 4, 64);
            p2 += __shfl_xor(p2, 4, 64); p3 += __shfl_xor(p3, 4, 64);
            const float w0 = __expf(p0), w1 = __expf(p1), w2 = __expf(p2), w3 = __expf(p3);
            acc.x += w0 * bf2f(va.x) + w1 * bf2f(vb.x) + w2 * bf2f(vc.x) + w3 * bf2f(vd.x);
            acc.y += w0 * bf2f(va.y) + w1 * bf2f(vb.y) + w2 * bf2f(vc.y) + w3 * bf2f(vd.y);
            acc.z += w0 * bf2f(va.z) + w1 * bf2f(vb.z) + w2 * bf2f(vc.z) + w3 * bf2f(vd.z);
            acc.w += w0 * bf2f(va.w) + w1 * bf2f(vb.w) + w2 * bf2f(vc.w) + w3 * bf2f(vd.w);
            dsum += (w0 + w1) + (w2 + w3);
        }
        for (; j < cnt; ++j) {
            const int s0 = __builtin_amdgcn_readlane(sv, j);
            const unsigned int qa = *reinterpret_cast<const unsigned int*>(qf8 + (size_t)s0 * 256 + lane * 4);
            const ushort4 va = *reinterpret_cast<const ushort4*>(kv + (size_t)s0 * 512 + 256 + lane * 4);
            float a0, a1, a2, a3;
            dec4_e4m3(qa, a0, a1, a2, a3);
            float p0 = a0 * k0 + a1 * k1 + a2 * k2 + a3 * k3;
            p0 += __shfl_xor(p0, 1, 64);
            p0 += __shfl_xor(p0, 2, 64);
            p0 += __shfl_xor(p0, 4, 64);
            const float w0 = __expf(p0);
            acc.x += w0 * bf2f(va.x);
            acc.y += w0 * bf2f(va.y);
            acc.z += w0 * bf2f(va.z);
            acc.w += w0 * bf2f(va.w);
            dsum += w0;
        }
    }
    const float inv = (deg > 0) ? 1.0f / dsum : 0.0f;

    const float4 th = *reinterpret_cast<const float4*>(
        triplet_h + (size_t)node * D + lane * 4);
    float4 xv;
    xv.x = th.x + acc.x * inv;
    xv.y = th.y + acc.y * inv;
    xv.z = th.z + acc.z * inv;
    xv.w = th.w + acc.w * inv;
    *reinterpret_cast<float4*>(x + (size_t)node * D + lane * 4) = xv;

    // LN2 across the wave
    float s  = xv.x + xv.y + xv.z + xv.w;
    float s2 = xv.x * xv.x + xv.y * xv.y + xv.z * xv.z + xv.w * xv.w;
#pragma unroll
    for (int o = 32; o > 0; o >>= 1) {
        s  += __shfl_xor(s,  o, 64);
        s2 += __shfl_xor(s2, o, 64);
    }
    const float mu  = s * (1.0f / D);
    const float var = s2 * (1.0f / D) - mu * mu;
    const float rs  = rsqrtf(var + LN_EPS);
    const float4 gg = *reinterpret_cast<const float4*>(g + lane * 4);
    const float4 bb = *reinterpret_cast<const float4*>(b + lane * 4);
    ushort4 o4;
    o4.x = f2bf((xv.x - mu) * rs * gg.x + bb.x);
    o4.y = f2bf((xv.y - mu) * rs * gg.y + bb.y);
    o4.z = f2bf((xv.z - mu) * rs * gg.z + bb.z);
    o4.w = f2bf((xv.w - mu) * rs * gg.w + bb.w);
    const size_t off = (((size_t)(node >> 4) * (D / 8) + (lane >> 1)) * 16 + (node & 15)) * 8
                       + (lane & 1) * 4;
    *reinterpret_cast<ushort4*>(xn + off) = o4;
}

// ---------------------------------------------------------------------------
extern "C" void kernel_launch(void* const* d_in, const int* in_sizes, int n_in,
                              void* d_out, int out_size, void* d_ws, size_t ws_size,
                              hipStream_t stream)
{
    const float* triplet_h = (const float*)d_in[0];
    const int*   src       = (const int*)d_in[1];
    const int*   dst       = (const int*)d_in[2];
    const float* Wqkv      = (const float*)d_in[3];
    const float* bqkv      = (const float*)d_in[4];
    const float* ln_attn_g = (const float*)d_in[5];
    const float* ln_attn_b = (const float*)d_in[6];
    const float* ln_res_g  = (const float*)d_in[7];
    const float* ln_res_b  = (const float*)d_in[8];
    const float* W_in      = (const float*)d_in[9];
    const float* b_in      = (const float*)d_in[10];
    const float* W_out     = (const float*)d_in[11];
    const float* b_out     = (const float*)d_in[12];
    float* out = (float*)d_out;

    // Workspace (~162 MB, under 245.76 MB ceiling):
    char* w = (char*)d_ws;
    unsigned short* bufA = (unsigned short*)w;   // kv bf16 row-major OR a1 bf16 frag
    w += (size_t)M_PAD * DFF * sizeof(unsigned short);
    unsigned short* h_xn = (unsigned short*)w;  w += (size_t)M_PAD * D * sizeof(unsigned short);
    float*          x    = (float*)w;           w += (size_t)N_NODES * D * sizeof(float);
    unsigned char*  qf8  = (unsigned char*)w;   w += (size_t)N_NODES * 256;
    unsigned short* Wqkv_pk = (unsigned short*)w; w += (size_t)D * D3 * sizeof(unsigned short);
    unsigned short* Win_pk  = (unsigned short*)w; w += (size_t)D * DFF * sizeof(unsigned short);
    unsigned short* Wout_pk = (unsigned short*)w; w += (size_t)DFF * D * sizeof(unsigned short);
    int* counts = (int*)w;  w += (size_t)N_NODES * sizeof(int);
    int* rowptr = (int*)w;  w += (size_t)(N_NODES + 1) * sizeof(int);
    int* cursor = (int*)w;  w += (size_t)N_NODES * sizeof(int);
    int* srcs   = (int*)w;  w += (size_t)N_EDGES * sizeof(int);

    unsigned short* kv = bufA;  // [40000][512] bf16 (k|v), dead after fused_attn
    unsigned short* a1 = bufA;  // [M_PAD/16][128][16][8] bf16 frag, live FFN only

    // ---- CSR build ----
    (void)hipMemsetAsync(counts, 0, (size_t)N_NODES * sizeof(int), stream);
    hist_kernel<<<N_EDGES / 256, 256, 0, stream>>>(dst, counts);
    scan_kernel<<<1, 1024, 0, stream>>>(counts, rowptr, cursor);
    fill_kernel<<<N_EDGES / 256, 256, 0, stream>>>(src, dst, cursor, srcs);

    // ---- weight packing (one launch) ----
    pack_all_kernel<<<352, 256, 0, stream>>>(Wqkv, W_in, W_out, Wqkv_pk, Win_pk, Wout_pk);

    // ---- main pipeline ----
    ln_bf_kernel<<<M_PAD / 4, 256, 0, stream>>>(triplet_h, ln_attn_g, ln_attn_b, h_xn);
    mfma_gemm_kernel<0, D, D3><<<((M_PAD / 128 + 7) / 8) * 8 * (D3 / 128), 256, 0, stream>>>(
        h_xn, Wqkv_pk, bqkv, qf8, kv, nullptr);
    fused_attn_kernel<<<N_NODES / 4, 256, 0, stream>>>(qf8, kv, srcs, rowptr, triplet_h,
                                                       ln_res_g, ln_res_b, x, h_xn);
    // kv dead; a1 overwrites it (EPI1 stores pad rows too -> no memset needed)
    mfma_gemm_kernel<1, D, DFF><<<((M_PAD / 128 + 7) / 8) * 8 * (DFF / 128), 256, 0, stream>>>(
        h_xn, Win_pk, b_in, a1, nullptr, nullptr);
    mfma_gemm_kernel<2, DFF, D><<<((M_PAD / 128 + 7) / 8) * 8 * (D / 128), 256, 0, stream>>>(
        a1, Wout_pk, b_out, out, nullptr, x);

    (void)in_sizes; (void)n_in; (void)out_size; (void)ws_size;
}

// Round 7
// 429.244 us; speedup vs baseline: 1.0637x; 1.0637x over previous
//
#include <hip/hip_runtime.h>
#include <math.h>

#define N_NODES 40000
#define M_PAD   40064      // 313 * 128
#define N_EDGES 640000
#define D       256
#define H       8
#define DFF     1024
#define D3      768
#define ATT_SCALE 0.0625f  // 256^-0.5
#define LN_EPS  1e-5f

typedef __attribute__((ext_vector_type(8))) short short8;
typedef __attribute__((ext_vector_type(4))) float f32x4;
typedef __attribute__((ext_vector_type(2))) float f32x2;

__device__ __forceinline__ unsigned short f2bf(float f) {
    unsigned int u = __builtin_bit_cast(unsigned int, f);
    u = (u + 0x7FFF + ((u >> 16) & 1)) >> 16;   // RTNE
    return (unsigned short)u;
}
__device__ __forceinline__ float bf2f(unsigned short u) {
    return __builtin_bit_cast(float, (unsigned int)u << 16);
}

// Fast exact-gelu: Abramowitz-Stegun 7.1.26 erf (|eps| <= 1.5e-7, branchless).
__device__ __forceinline__ float fast_gelu(float x) {
    const float z  = fabsf(x) * 0.70710678118654752f;
    const float t  = __builtin_amdgcn_rcpf(1.0f + 0.3275911f * z);
    float p = 1.061405429f;
    p = p * t - 1.453152027f;
    p = p * t + 1.421413741f;
    p = p * t - 0.284496736f;
    p = p * t + 0.254829592f;
    const float e  = __expf(-z * z);
    const float ea = 1.0f - p * t * e;          // erf(|x|/sqrt2)
    const float er = (x < 0.0f) ? -ea : ea;
    return 0.5f * x * (1.0f + er);
}

#define GLOAD_LDS16(g, l) \
    __builtin_amdgcn_global_load_lds((const __attribute__((address_space(1))) void*)(g), \
                                     (__attribute__((address_space(3))) void*)(l), 16, 0, 0)

// ---------------- fp8 e4m3 pack/unpack (HW cvt on gfx950, SW fallback) -----
#if __has_builtin(__builtin_amdgcn_cvt_pk_fp8_f32) && __has_builtin(__builtin_amdgcn_cvt_pk_f32_fp8)
#define HW_FP8 1
#else
#define HW_FP8 0
__device__ __forceinline__ unsigned char enc_e4m3(float f) {
    unsigned int u = __builtin_bit_cast(unsigned int, f);
    unsigned int s = (u >> 24) & 0x80;
    float a = fabsf(f);
    if (a >= 0x1p-6f) {
        unsigned int bits = __builtin_bit_cast(unsigned int, a);
        unsigned int q = bits >> 20;
        unsigned int rem = bits & 0xFFFFFu;
        q += (rem > 0x80000u) || ((rem == 0x80000u) && (q & 1));
        q -= 960;                          // rebias (120<<3)
        if (q > 126) q = 126;              // clamp to 448
        return (unsigned char)(s | q);
    }
    float t = a * 512.0f;
    unsigned int r = (unsigned int)rintf(t);   // RNE; 8 -> min normal naturally
    return (unsigned char)(s | r);
}
__device__ __forceinline__ float dec_e4m3(unsigned int v) {
    unsigned int em = v & 0x7f;
    float n = __builtin_bit_cast(float, (em << 20) + 0x3C000000u);
    float r = (em >= 8) ? n : (float)em * 0x1p-9f;
    return (v & 0x80) ? -r : r;
}
#endif

__device__ __forceinline__ unsigned int pack4_e4m3(float a, float b, float c, float d) {
#if HW_FP8
    unsigned int w = (unsigned int)__builtin_amdgcn_cvt_pk_fp8_f32(a, b, 0, false);
    w = (unsigned int)__builtin_amdgcn_cvt_pk_fp8_f32(c, d, (int)w, true);
    return w;
#else
    return (unsigned int)enc_e4m3(a) | ((unsigned int)enc_e4m3(b) << 8)
         | ((unsigned int)enc_e4m3(c) << 16) | ((unsigned int)enc_e4m3(d) << 24);
#endif
}
__device__ __forceinline__ void dec4_e4m3(unsigned int w, float& a, float& b, float& c, float& d) {
#if HW_FP8
    f32x2 lo = __builtin_amdgcn_cvt_pk_f32_fp8((int)w, false);
    f32x2 hi = __builtin_amdgcn_cvt_pk_f32_fp8((int)w, true);
    a = lo[0]; b = lo[1]; c = hi[0]; d = hi[1];
#else
    a = dec_e4m3(w & 0xff); b = dec_e4m3((w >> 8) & 0xff);
    c = dec_e4m3((w >> 16) & 0xff); d = dec_e4m3(w >> 24);
#endif
}

// ---------------------------------------------------------------------------
// LayerNorm -> bf16 output in MFMA A-fragment order [M/16][D/8][16][8].
// Covers pad rows [N_NODES, M_PAD) with zeros (replaces a memset).
// ---------------------------------------------------------------------------
__global__ __launch_bounds__(256) void ln_bf_kernel(const float* __restrict__ in,
                                                    const float* __restrict__ g,
                                                    const float* __restrict__ b,
                                                    unsigned short* __restrict__ out)
{
    const int row  = blockIdx.x * 4 + (threadIdx.x >> 6);
    const int lane = threadIdx.x & 63;
    const size_t off = (((size_t)(row >> 4) * (D / 8) + (lane >> 1)) * 16 + (row & 15)) * 8
                       + (lane & 1) * 4;
    if (row >= N_NODES) {
        ushort4 z = {0, 0, 0, 0};
        *reinterpret_cast<ushort4*>(out + off) = z;
        return;
    }
    const float4 v = *reinterpret_cast<const float4*>(in + (size_t)row * D + lane * 4);
    float s  = v.x + v.y + v.z + v.w;
    float s2 = v.x * v.x + v.y * v.y + v.z * v.z + v.w * v.w;
#pragma unroll
    for (int o = 32; o > 0; o >>= 1) {
        s  += __shfl_xor(s,  o, 64);
        s2 += __shfl_xor(s2, o, 64);
    }
    const float mu  = s * (1.0f / D);
    const float var = s2 * (1.0f / D) - mu * mu;
    const float rs  = rsqrtf(var + LN_EPS);
    const float4 gg = *reinterpret_cast<const float4*>(g + lane * 4);
    const float4 bb = *reinterpret_cast<const float4*>(b + lane * 4);
    ushort4 o4;
    o4.x = f2bf((v.x - mu) * rs * gg.x + bb.x);
    o4.y = f2bf((v.y - mu) * rs * gg.y + bb.y);
    o4.z = f2bf((v.z - mu) * rs * gg.z + bb.z);
    o4.w = f2bf((v.w - mu) * rs * gg.w + bb.w);
    *reinterpret_cast<ushort4*>(out + off) = o4;
}

// ---------------------------------------------------------------------------
// Weight pack: W[K][N] fp32 -> bf16 packed [N/16][K/8][16][8]. All three
// weights in ONE kernel (one launch).
// ---------------------------------------------------------------------------
template <int K, int N>
__device__ __forceinline__ void pack_body(const float* __restrict__ W,
                                          unsigned short* __restrict__ Wpk, int blk)
{
    const int idx = blk * 256 + threadIdx.x;   // [N/16][K/8][16]
    const int ni  = idx & 15;
    const int kc  = (idx >> 4) % (K / 8);
    const int nt  = idx / (16 * (K / 8));
    const int n   = nt * 16 + ni;
    unsigned short o[8];
#pragma unroll
    for (int i = 0; i < 8; ++i)
        o[i] = f2bf(W[(size_t)(kc * 8 + i) * N + n]);
    *reinterpret_cast<short8*>(Wpk + (size_t)idx * 8) = *reinterpret_cast<short8*>(o);
}

__global__ __launch_bounds__(256) void pack_all_kernel(const float* __restrict__ Wqkv,
                                                       const float* __restrict__ W_in,
                                                       const float* __restrict__ W_out,
                                                       unsigned short* __restrict__ pq,
                                                       unsigned short* __restrict__ pi,
                                                       unsigned short* __restrict__ po)
{
    const int b = blockIdx.x;
    if (b < 96)       pack_body<D, D3 >(Wqkv, pq, b);
    else if (b < 224) pack_body<D, DFF>(W_in, pi, b - 96);
    else              pack_body<DFF, D>(W_out, po, b - 224);
}

// ---------------------------------------------------------------------------
// bf16 MFMA GEMM -- m97 staging structure (round-5 best: 128x128 tile,
// 4 waves, BK=32, global_load_lds width 16, barrier-synced K loop), LDS
// 16 KB, 4 blocks/CU. Panel-colocating XCD swizzle. MFMA operands SWAPPED:
// D maps to row r = lane&15, cols n = (lane>>4)*4+t -> 4 consecutive cols.
// EPI 0: qkv 3-way split -> q fp8 (unscaled), k bf16 [node][256], v fp8
// EPI 1: bf16 C in fragment order [M/16][N/8][16][8] + fast exact gelu
// EPI 2: fp32 C row-major += Xadd, nontemporal f32x4 load/store
// ---------------------------------------------------------------------------
template <int EPI, int K, int N>
__global__ __launch_bounds__(256, 4) void mfma_gemm_kernel(const unsigned short* __restrict__ A,
                                                           const unsigned short* __restrict__ Bpk,
                                                           const float* __restrict__ bias,
                                                           void* __restrict__ Cout,
                                                           void* __restrict__ Cout2,
                                                           void* __restrict__ Cout3,
                                                           const float* __restrict__ Xadd)
{
    constexpr int C = N / 128;           // col tiles
    constexpr int P = M_PAD / 128;       // 313 row panels

    const int bid = blockIdx.x;
    const int xcd = bid & 7;
    const int t   = bid >> 3;
    const int c   = t % C;
    const int p   = (t / C) * 8 + xcd;
    if (p >= P) return;

    __shared__ unsigned short As[4096];   // [mt8][16][8] = 8 KB
    __shared__ unsigned short Bs[4096];

    const int tid  = threadIdx.x;
    const int wave = tid >> 6;
    const int lane = tid & 63;
    const int row0 = p * 128;
    const int col0 = c * 128;
    const int wm   = (wave >> 1) * 64;
    const int wn   = (wave & 1) * 64;
    const int g    = lane >> 4;
    const int q    = lane & 15;

    f32x4 acc[4][4] = {};

    const int fragoff = g * 128 + q * 8;

    for (int k0 = 0; k0 < K; k0 += 32) {
        const int kq = k0 >> 3;   // k-chunk index (K/8 units)
#pragma unroll
        for (int cc = 0; cc < 2; ++cc) {
            const int mt = wave * 2 + cc;                // 0..7
            const unsigned short* gA =
                A + ((size_t)(row0 / 16 + mt) * (K / 8) + kq) * 128 + lane * 8;
            GLOAD_LDS16(gA, &As[mt * 512]);
            const unsigned short* gB =
                Bpk + ((size_t)(col0 / 16 + mt) * (K / 8) + kq) * 128 + lane * 8;
            GLOAD_LDS16(gB, &Bs[mt * 512]);
        }
        __syncthreads();

        short8 af[4], bf[4];
#pragma unroll
        for (int i = 0; i < 4; ++i) {
            af[i] = *reinterpret_cast<const short8*>(&As[(wm / 16 + i) * 512 + fragoff]);
            bf[i] = *reinterpret_cast<const short8*>(&Bs[(wn / 16 + i) * 512 + fragoff]);
        }
#pragma unroll
        for (int i = 0; i < 4; ++i)
#pragma unroll
            for (int j = 0; j < 4; ++j)
                acc[i][j] = __builtin_amdgcn_mfma_f32_16x16x32_bf16(bf[j], af[i], acc[i][j], 0, 0, 0);
        __syncthreads();
    }

    // Swapped D layout: r = row0+wm+i*16+q ; n = col0+wn+j*16+g*4+t (t=0..3)
    if constexpr (EPI == 0) {
        if (col0 < 256) {        // q cols -> fp8, UNSCALED (scale folded into k)
            unsigned char* q8 = (unsigned char*)Cout;
#pragma unroll
            for (int j = 0; j < 4; ++j) {
                const int nb = col0 + wn + j * 16 + g * 4;
                const float4 bz = *reinterpret_cast<const float4*>(bias + nb);
#pragma unroll
                for (int i = 0; i < 4; ++i) {
                    const int r = row0 + wm + i * 16 + q;
                    if (r >= N_NODES) continue;
                    const unsigned int w = pack4_e4m3(acc[i][j][0] + bz.x, acc[i][j][1] + bz.y,
                                                      acc[i][j][2] + bz.z, acc[i][j][3] + bz.w);
                    *reinterpret_cast<unsigned int*>(q8 + (size_t)r * 256 + nb) = w;
                }
            }
        } else if (col0 < 512) { // k cols -> bf16 row-major [node][256]
            unsigned short* kb = (unsigned short*)Cout2;
#pragma unroll
            for (int j = 0; j < 4; ++j) {
                const int nb = col0 + wn + j * 16 + g * 4;
                const float4 bz = *reinterpret_cast<const float4*>(bias + nb);
#pragma unroll
                for (int i = 0; i < 4; ++i) {
                    const int r = row0 + wm + i * 16 + q;
                    if (r >= N_NODES) continue;
                    ushort4 u;
                    u.x = f2bf(acc[i][j][0] + bz.x);
                    u.y = f2bf(acc[i][j][1] + bz.y);
                    u.z = f2bf(acc[i][j][2] + bz.z);
                    u.w = f2bf(acc[i][j][3] + bz.w);
                    *reinterpret_cast<ushort4*>(kb + (size_t)r * 256 + (nb - 256)) = u;
                }
            }
        } else {                 // v cols -> fp8 [node][256]
            unsigned char* v8 = (unsigned char*)Cout3;
#pragma unroll
            for (int j = 0; j < 4; ++j) {
                const int nb = col0 + wn + j * 16 + g * 4;
                const float4 bz = *reinterpret_cast<const float4*>(bias + nb);
#pragma unroll
                for (int i = 0; i < 4; ++i) {
                    const int r = row0 + wm + i * 16 + q;
                    if (r >= N_NODES) continue;
                    const unsigned int w = pack4_e4m3(acc[i][j][0] + bz.x, acc[i][j][1] + bz.y,
                                                      acc[i][j][2] + bz.z, acc[i][j][3] + bz.w);
                    *reinterpret_cast<unsigned int*>(v8 + (size_t)r * 256 + (nb - 512)) = w;
                }
            }
        }
    } else if constexpr (EPI == 1) {
#pragma unroll
        for (int j = 0; j < 4; ++j) {
            const int nb = col0 + wn + j * 16 + g * 4;
            const float4 bz = *reinterpret_cast<const float4*>(bias + nb);
#pragma unroll
            for (int i = 0; i < 4; ++i) {
                const int r = row0 + wm + i * 16 + q;   // pad rows stored too (finite)
                const float o0 = fast_gelu(acc[i][j][0] + bz.x);
                const float o1 = fast_gelu(acc[i][j][1] + bz.y);
                const float o2 = fast_gelu(acc[i][j][2] + bz.z);
                const float o3 = fast_gelu(acc[i][j][3] + bz.w);
                const size_t off = (((size_t)(r >> 4) * (N / 8) + (nb >> 3)) * 16
                                    + (r & 15)) * 8 + (nb & 7);
                ushort4 u;
                u.x = f2bf(o0); u.y = f2bf(o1); u.z = f2bf(o2); u.w = f2bf(o3);
                *reinterpret_cast<ushort4*>((unsigned short*)Cout + off) = u;
            }
        }
    } else {
#pragma unroll
        for (int j = 0; j < 4; ++j) {
            const int nb = col0 + wn + j * 16 + g * 4;
            const float4 bz = *reinterpret_cast<const float4*>(bias + nb);
#pragma unroll
            for (int i = 0; i < 4; ++i) {
                const int r = row0 + wm + i * 16 + q;
                if (r >= N_NODES) continue;
                const f32x4 xd = __builtin_nontemporal_load(
                    reinterpret_cast<const f32x4*>(Xadd + (size_t)r * N + nb));
                f32x4 ov;
                ov[0] = acc[i][j][0] + bz.x + xd[0];
                ov[1] = acc[i][j][1] + bz.y + xd[1];
                ov[2] = acc[i][j][2] + bz.z + xd[2];
                ov[3] = acc[i][j][3] + bz.w + xd[3];
                __builtin_nontemporal_store(ov,
                    reinterpret_cast<f32x4*>((float*)Cout + (size_t)r * N + nb));
            }
        }
    }
}

// ---------------------------------------------------------------------------
// CSR build
// ---------------------------------------------------------------------------
__global__ __launch_bounds__(256) void hist_kernel(const int* __restrict__ dst,
                                                   int* __restrict__ counts)
{
    const int i = blockIdx.x * 256 + threadIdx.x;
    atomicAdd(&counts[dst[i]], 1);
}

__global__ __launch_bounds__(1024) void scan_kernel(const int* __restrict__ counts,
                                                    int* __restrict__ rowptr,
                                                    int* __restrict__ cursor)
{
    const int PER = 40;
    const int tid  = threadIdx.x;
    const int base = tid * PER;
    int c[PER];
    int s = 0;
#pragma unroll
    for (int i = 0; i < PER; ++i) {
        const int idx = base + i;
        c[i] = (idx < N_NODES) ? counts[idx] : 0;
        s += c[i];
    }
    __shared__ int sm[1024];
    sm[tid] = s;
    __syncthreads();
    for (int off = 1; off < 1024; off <<= 1) {
        int t = (tid >= off) ? sm[tid - off] : 0;
        __syncthreads();
        sm[tid] += t;
        __syncthreads();
    }
    int run = sm[tid] - s;
#pragma unroll
    for (int i = 0; i < PER; ++i) {
        const int idx = base + i;
        if (idx < N_NODES) {
            rowptr[idx] = run;
            cursor[idx] = run;
            run += c[i];
        }
    }
    if (tid == 1023) rowptr[N_NODES] = sm[1023];
}

__global__ __launch_bounds__(256) void fill_kernel(const int* __restrict__ src,
                                                   const int* __restrict__ dst,
                                                   int* __restrict__ cursor,
                                                   int* __restrict__ srcs)
{
    const int e = blockIdx.x * 256 + threadIdx.x;
    const int pos = atomicAdd(&cursor[dst[e]], 1);
    if (pos >= 0 && pos < N_EDGES) srcs[pos] = src[e];
}

// ---------------------------------------------------------------------------
// Fused attention: q fp8 (256 B/row, gathered) + v fp8 (256 B/row, gathered)
// + k bf16 (512 B/row, loaded once per dst node). Edge gather = 512 B
// (was 768). One wave per dst node; src list coalesce-prefetched, readlane
// broadcast, 4-edge unroll. k scaled by ATT_SCALE at load.
// Outputs: x fp32 row-major, xn bf16 in fragment order.
// ---------------------------------------------------------------------------
__global__ __launch_bounds__(256) void fused_attn_kernel(const unsigned char* __restrict__ qf8,
                                                         const unsigned short* __restrict__ kbf,
                                                         const unsigned char* __restrict__ vf8,
                                                         const int* __restrict__ srcs,
                                                         const int* __restrict__ rowptr,
                                                         const float* __restrict__ triplet_h,
                                                         const float* __restrict__ g,
                                                         const float* __restrict__ b,
                                                         float* __restrict__ x,
                                                         unsigned short* __restrict__ xn)
{
    const int node = blockIdx.x * 4 + (threadIdx.x >> 6);
    const int lane = threadIdx.x & 63;
    int beg = rowptr[node];
    int end = rowptr[node + 1];
    beg = max(0, min(beg, N_EDGES));
    end = max(beg, min(end, N_EDGES));
    const int deg = end - beg;

    const ushort4 ku = *reinterpret_cast<const ushort4*>(
        kbf + (size_t)node * 256 + lane * 4);
    const float k0 = bf2f(ku.x) * ATT_SCALE, k1 = bf2f(ku.y) * ATT_SCALE;
    const float k2 = bf2f(ku.z) * ATT_SCALE, k3 = bf2f(ku.w) * ATT_SCALE;

    float dsum = 0.0f;
    float4 acc = {0.0f, 0.0f, 0.0f, 0.0f};

    for (int base = 0; base < deg; base += 64) {
        const int cnt = min(64, deg - base);
        const int idx = base + lane;
        const int sv = (idx < deg) ? srcs[beg + idx] : 0;   // coalesced prefetch
        int j = 0;
        for (; j + 4 <= cnt; j += 4) {
            const int s0 = __builtin_amdgcn_readlane(sv, j);
            const int s1 = __builtin_amdgcn_readlane(sv, j + 1);
            const int s2 = __builtin_amdgcn_readlane(sv, j + 2);
            const int s3 = __builtin_amdgcn_readlane(sv, j + 3);
            const unsigned int qa = *reinterpret_cast<const unsigned int*>(qf8 + (size_t)s0 * 256 + lane * 4);
            const unsigned int qb = *reinterpret_cast<const unsigned int*>(qf8 + (size_t)s1 * 256 + lane * 4);
            const unsigned int qc = *reinterpret_cast<const unsigned int*>(qf8 + (size_t)s2 * 256 + lane * 4);
            const unsigned int qd = *reinterpret_cast<const unsigned int*>(qf8 + (size_t)s3 * 256 + lane * 4);
            const unsigned int va = *reinterpret_cast<const unsigned int*>(vf8 + (size_t)s0 * 256 + lane * 4);
            const unsigned int vb = *reinterpret_cast<const unsigned int*>(vf8 + (size_t)s1 * 256 + lane * 4);
            const unsigned int vc = *reinterpret_cast<const unsigned int*>(vf8 + (size_t)s2 * 256 + lane * 4);
            const unsigned int vd = *reinterpret_cast<const unsigned int*>(vf8 + (size_t)s3 * 256 + lane * 4);
            float a0, a1, a2, a3;
            dec4_e4m3(qa, a0, a1, a2, a3);
            float p0 = a0 * k0 + a1 * k1 + a2 * k2 + a3 * k3;
            dec4_e4m3(qb, a0, a1, a2, a3);
            float p1 = a0 * k0 + a1 * k1 + a2 * k2 + a3 * k3;
            dec4_e4m3(qc, a0, a1, a2, a3);
            float p2 = a0 * k0 + a1 * k1 + a2 * k2 + a3 * k3;
            dec4_e4m3(qd, a0, a1, a2, a3);
            float p3 = a0 * k0 + a1 * k1 + a2 * k2 + a3 * k3;
            p0 += __shfl_xor(p0, 1, 64); p1 += __shfl_xor(p1, 1, 64);
            p2 += __shfl_xor(p2, 1, 64); p3 += __shfl_xor(p3, 1, 64);
            p0 += __shfl_xor(p0, 2, 64); p1 += __shfl_xor(p1, 2, 64);
            p2 += __shfl_xor(p2, 2, 64); p3 += __shfl_xor(p3, 2, 64);
            p0 += __shfl_xor(p0, 4, 64); p1 += __shfl_xor(p1, 4, 64);
            p2 += __shfl_xor(p2, 4, 64); p3 += __shfl_xor(p3, 4, 64);
            const float w0 = __expf(p0), w1 = __expf(p1), w2 = __expf(p2), w3 = __expf(p3);
            float v0, v1, v2, v3;
            dec4_e4m3(va, v0, v1, v2, v3);
            acc.x += w0 * v0; acc.y += w0 * v1; acc.z += w0 * v2; acc.w += w0 * v3;
            dec4_e4m3(vb, v0, v1, v2, v3);
            acc.x += w1 * v0; acc.y += w1 * v1; acc.z += w1 * v2; acc.w += w1 * v3;
            dec4_e4m3(vc, v0, v1, v2, v3);
            acc.x += w2 * v0; acc.y += w2 * v1; acc.z += w2 * v2; acc.w += w2 * v3;
            dec4_e4m3(vd, v0, v1, v2, v3);
            acc.x += w3 * v0; acc.y += w3 * v1; acc.z += w3 * v2; acc.w += w3 * v3;
            dsum += (w0 + w1) + (w2 + w3);
        }
        for (; j < cnt; ++j) {
            const int s0 = __builtin_amdgcn_readlane(sv, j);
            const unsigned int qa = *reinterpret_cast<const unsigned int*>(qf8 + (size_t)s0 * 256 + lane * 4);
            const unsigned int va = *reinterpret_cast<const unsigned int*>(vf8 + (size_t)s0 * 256 + lane * 4);
            float a0, a1, a2, a3;
            dec4_e4m3(qa, a0, a1, a2, a3);
            float p0 = a0 * k0 + a1 * k1 + a2 * k2 + a3 * k3;
            p0 += __shfl_xor(p0, 1, 64);
            p0 += __shfl_xor(p0, 2, 64);
            p0 += __shfl_xor(p0, 4, 64);
            const float w0 = __expf(p0);
            float v0, v1, v2, v3;
            dec4_e4m3(va, v0, v1, v2, v3);
            acc.x += w0 * v0; acc.y += w0 * v1; acc.z += w0 * v2; acc.w += w0 * v3;
            dsum += w0;
        }
    }
    const float inv = (deg > 0) ? 1.0f / dsum : 0.0f;

    const float4 th = *reinterpret_cast<const float4*>(
        triplet_h + (size_t)node * D + lane * 4);
    float4 xv;
    xv.x = th.x + acc.x * inv;
    xv.y = th.y + acc.y * inv;
    xv.z = th.z + acc.z * inv;
    xv.w = th.w + acc.w * inv;
    *reinterpret_cast<float4*>(x + (size_t)node * D + lane * 4) = xv;

    // LN2 across the wave
    float s  = xv.x + xv.y + xv.z + xv.w;
    float s2 = xv.x * xv.x + xv.y * xv.y + xv.z * xv.z + xv.w * xv.w;
#pragma unroll
    for (int o = 32; o > 0; o >>= 1) {
        s  += __shfl_xor(s,  o, 64);
        s2 += __shfl_xor(s2, o, 64);
    }
    const float mu  = s * (1.0f / D);
    const float var = s2 * (1.0f / D) - mu * mu;
    const float rs  = rsqrtf(var + LN_EPS);
    const float4 gg = *reinterpret_cast<const float4*>(g + lane * 4);
    const float4 bb = *reinterpret_cast<const float4*>(b + lane * 4);
    ushort4 o4;
    o4.x = f2bf((xv.x - mu) * rs * gg.x + bb.x);
    o4.y = f2bf((xv.y - mu) * rs * gg.y + bb.y);
    o4.z = f2bf((xv.z - mu) * rs * gg.z + bb.z);
    o4.w = f2bf((xv.w - mu) * rs * gg.w + bb.w);
    const size_t off = (((size_t)(node >> 4) * (D / 8) + (lane >> 1)) * 16 + (node & 15)) * 8
                       + (lane & 1) * 4;
    *reinterpret_cast<ushort4*>(xn + off) = o4;
}

// ---------------------------------------------------------------------------
extern "C" void kernel_launch(void* const* d_in, const int* in_sizes, int n_in,
                              void* d_out, int out_size, void* d_ws, size_t ws_size,
                              hipStream_t stream)
{
    const float* triplet_h = (const float*)d_in[0];
    const int*   src       = (const int*)d_in[1];
    const int*   dst       = (const int*)d_in[2];
    const float* Wqkv      = (const float*)d_in[3];
    const float* bqkv      = (const float*)d_in[4];
    const float* ln_attn_g = (const float*)d_in[5];
    const float* ln_attn_b = (const float*)d_in[6];
    const float* ln_res_g  = (const float*)d_in[7];
    const float* ln_res_b  = (const float*)d_in[8];
    const float* W_in      = (const float*)d_in[9];
    const float* b_in      = (const float*)d_in[10];
    const float* W_out     = (const float*)d_in[11];
    const float* b_out     = (const float*)d_in[12];
    float* out = (float*)d_out;

    // Workspace (~175 MB, under 245.76 MB ceiling):
    char* w = (char*)d_ws;
    unsigned short* bufA = (unsigned short*)w;   // kbf (EPI0 out) OR a1 bf16 frag
    w += (size_t)M_PAD * DFF * sizeof(unsigned short);
    unsigned short* h_xn = (unsigned short*)w;  w += (size_t)M_PAD * D * sizeof(unsigned short);
    float*          x    = (float*)w;           w += (size_t)N_NODES * D * sizeof(float);
    unsigned char*  qf8  = (unsigned char*)w;   w += (size_t)N_NODES * 256;
    unsigned char*  vf8  = (unsigned char*)w;   w += (size_t)N_NODES * 256;
    unsigned short* Wqkv_pk = (unsigned short*)w; w += (size_t)D * D3 * sizeof(unsigned short);
    unsigned short* Win_pk  = (unsigned short*)w; w += (size_t)D * DFF * sizeof(unsigned short);
    unsigned short* Wout_pk = (unsigned short*)w; w += (size_t)DFF * D * sizeof(unsigned short);
    int* counts = (int*)w;  w += (size_t)N_NODES * sizeof(int);
    int* rowptr = (int*)w;  w += (size_t)(N_NODES + 1) * sizeof(int);
    int* cursor = (int*)w;  w += (size_t)N_NODES * sizeof(int);
    int* srcs   = (int*)w;  w += (size_t)N_EDGES * sizeof(int);

    unsigned short* kbf = bufA;  // [40000][256] bf16 (k), dead after fused_attn
    unsigned short* a1  = bufA;  // [M_PAD/16][128][16][8] bf16 frag, live FFN only

    // ---- CSR build ----
    (void)hipMemsetAsync(counts, 0, (size_t)N_NODES * sizeof(int), stream);
    hist_kernel<<<N_EDGES / 256, 256, 0, stream>>>(dst, counts);
    scan_kernel<<<1, 1024, 0, stream>>>(counts, rowptr, cursor);
    fill_kernel<<<N_EDGES / 256, 256, 0, stream>>>(src, dst, cursor, srcs);

    // ---- weight packing (one launch) ----
    pack_all_kernel<<<352, 256, 0, stream>>>(Wqkv, W_in, W_out, Wqkv_pk, Win_pk, Wout_pk);

    // ---- main pipeline ----
    ln_bf_kernel<<<M_PAD / 4, 256, 0, stream>>>(triplet_h, ln_attn_g, ln_attn_b, h_xn);
    mfma_gemm_kernel<0, D, D3><<<((M_PAD / 128 + 7) / 8) * 8 * (D3 / 128), 256, 0, stream>>>(
        h_xn, Wqkv_pk, bqkv, qf8, kbf, vf8, nullptr);
    fused_attn_kernel<<<N_NODES / 4, 256, 0, stream>>>(qf8, kbf, vf8, srcs, rowptr, triplet_h,
                                                       ln_res_g, ln_res_b, x, h_xn);
    // kbf dead; a1 overwrites it (EPI1 stores pad rows too -> no memset needed)
    mfma_gemm_kernel<1, D, DFF><<<((M_PAD / 128 + 7) / 8) * 8 * (DFF / 128), 256, 0, stream>>>(
        h_xn, Win_pk, b_in, a1, nullptr, nullptr, nullptr);
    mfma_gemm_kernel<2, DFF, D><<<((M_PAD / 128 + 7) / 8) * 8 * (D / 128), 256, 0, stream>>>(
        a1, Wout_pk, b_out, out, nullptr, nullptr, x);

    (void)in_sizes; (void)n_in; (void)out_size; (void)ws_size;
}

// Round 8
// 385.198 us; speedup vs baseline: 1.1854x; 1.1143x over previous
//
#include <hip/hip_runtime.h>
#include <math.h>

#define N_NODES 40000
#define M_PAD   40064      // 313 * 128
#define N_EDGES 640000
#define D       256
#define H       8
#define DFF     1024
#define D3      768
#define ATT_SCALE 0.0625f  // 256^-0.5
#define LN_EPS  1e-5f

typedef __attribute__((ext_vector_type(8))) short short8;
typedef __attribute__((ext_vector_type(4))) float f32x4;
typedef __attribute__((ext_vector_type(2))) float f32x2;

__device__ __forceinline__ unsigned short f2bf(float f) {
    unsigned int u = __builtin_bit_cast(unsigned int, f);
    u = (u + 0x7FFF + ((u >> 16) & 1)) >> 16;   // RTNE
    return (unsigned short)u;
}
__device__ __forceinline__ float bf2f(unsigned short u) {
    return __builtin_bit_cast(float, (unsigned int)u << 16);
}

// Fast exact-gelu: Abramowitz-Stegun 7.1.26 erf (|eps| <= 1.5e-7, branchless).
__device__ __forceinline__ float fast_gelu(float x) {
    const float z  = fabsf(x) * 0.70710678118654752f;
    const float t  = __builtin_amdgcn_rcpf(1.0f + 0.3275911f * z);
    float p = 1.061405429f;
    p = p * t - 1.453152027f;
    p = p * t + 1.421413741f;
    p = p * t - 0.284496736f;
    p = p * t + 0.254829592f;
    const float e  = __expf(-z * z);
    const float ea = 1.0f - p * t * e;          // erf(|x|/sqrt2)
    const float er = (x < 0.0f) ? -ea : ea;
    return 0.5f * x * (1.0f + er);
}

#define GLOAD_LDS16(g, l) \
    __builtin_amdgcn_global_load_lds((const __attribute__((address_space(1))) void*)(g), \
                                     (__attribute__((address_space(3))) void*)(l), 16, 0, 0)

// ---------------- fp8 e4m3 pack/unpack (HW cvt on gfx950, SW fallback) -----
#if __has_builtin(__builtin_amdgcn_cvt_pk_fp8_f32) && __has_builtin(__builtin_amdgcn_cvt_pk_f32_fp8)
#define HW_FP8 1
#else
#define HW_FP8 0
__device__ __forceinline__ unsigned char enc_e4m3(float f) {
    unsigned int u = __builtin_bit_cast(unsigned int, f);
    unsigned int s = (u >> 24) & 0x80;
    float a = fabsf(f);
    if (a >= 0x1p-6f) {
        unsigned int bits = __builtin_bit_cast(unsigned int, a);
        unsigned int q = bits >> 20;
        unsigned int rem = bits & 0xFFFFFu;
        q += (rem > 0x80000u) || ((rem == 0x80000u) && (q & 1));
        q -= 960;                          // rebias (120<<3)
        if (q > 126) q = 126;              // clamp to 448
        return (unsigned char)(s | q);
    }
    float t = a * 512.0f;
    unsigned int r = (unsigned int)rintf(t);   // RNE; 8 -> min normal naturally
    return (unsigned char)(s | r);
}
__device__ __forceinline__ float dec_e4m3(unsigned int v) {
    unsigned int em = v & 0x7f;
    float n = __builtin_bit_cast(float, (em << 20) + 0x3C000000u);
    float r = (em >= 8) ? n : (float)em * 0x1p-9f;
    return (v & 0x80) ? -r : r;
}
#endif

__device__ __forceinline__ unsigned int pack4_e4m3(float a, float b, float c, float d) {
#if HW_FP8
    unsigned int w = (unsigned int)__builtin_amdgcn_cvt_pk_fp8_f32(a, b, 0, false);
    w = (unsigned int)__builtin_amdgcn_cvt_pk_fp8_f32(c, d, (int)w, true);
    return w;
#else
    return (unsigned int)enc_e4m3(a) | ((unsigned int)enc_e4m3(b) << 8)
         | ((unsigned int)enc_e4m3(c) << 16) | ((unsigned int)enc_e4m3(d) << 24);
#endif
}
__device__ __forceinline__ void dec4_e4m3(unsigned int w, float& a, float& b, float& c, float& d) {
#if HW_FP8
    f32x2 lo = __builtin_amdgcn_cvt_pk_f32_fp8((int)w, false);
    f32x2 hi = __builtin_amdgcn_cvt_pk_f32_fp8((int)w, true);
    a = lo[0]; b = lo[1]; c = hi[0]; d = hi[1];
#else
    a = dec_e4m3(w & 0xff); b = dec_e4m3((w >> 8) & 0xff);
    c = dec_e4m3((w >> 16) & 0xff); d = dec_e4m3(w >> 24);
#endif
}

// ---------------------------------------------------------------------------
// LayerNorm -> bf16 output in MFMA A-fragment order [M/16][D/8][16][8].
// Covers pad rows [N_NODES, M_PAD) with zeros (replaces a memset).
// ---------------------------------------------------------------------------
__global__ __launch_bounds__(256) void ln_bf_kernel(const float* __restrict__ in,
                                                    const float* __restrict__ g,
                                                    const float* __restrict__ b,
                                                    unsigned short* __restrict__ out)
{
    const int row  = blockIdx.x * 4 + (threadIdx.x >> 6);
    const int lane = threadIdx.x & 63;
    const size_t off = (((size_t)(row >> 4) * (D / 8) + (lane >> 1)) * 16 + (row & 15)) * 8
                       + (lane & 1) * 4;
    if (row >= N_NODES) {
        ushort4 z = {0, 0, 0, 0};
        *reinterpret_cast<ushort4*>(out + off) = z;
        return;
    }
    const float4 v = *reinterpret_cast<const float4*>(in + (size_t)row * D + lane * 4);
    float s  = v.x + v.y + v.z + v.w;
    float s2 = v.x * v.x + v.y * v.y + v.z * v.z + v.w * v.w;
#pragma unroll
    for (int o = 32; o > 0; o >>= 1) {
        s  += __shfl_xor(s,  o, 64);
        s2 += __shfl_xor(s2, o, 64);
    }
    const float mu  = s * (1.0f / D);
    const float var = s2 * (1.0f / D) - mu * mu;
    const float rs  = rsqrtf(var + LN_EPS);
    const float4 gg = *reinterpret_cast<const float4*>(g + lane * 4);
    const float4 bb = *reinterpret_cast<const float4*>(b + lane * 4);
    ushort4 o4;
    o4.x = f2bf((v.x - mu) * rs * gg.x + bb.x);
    o4.y = f2bf((v.y - mu) * rs * gg.y + bb.y);
    o4.z = f2bf((v.z - mu) * rs * gg.z + bb.z);
    o4.w = f2bf((v.w - mu) * rs * gg.w + bb.w);
    *reinterpret_cast<ushort4*>(out + off) = o4;
}

// ---------------------------------------------------------------------------
// Weight pack: W[K][N] fp32 -> bf16 packed [N/16][K/8][16][8]. All three
// weights in ONE kernel (one launch).
// ---------------------------------------------------------------------------
template <int K, int N>
__device__ __forceinline__ void pack_body(const float* __restrict__ W,
                                          unsigned short* __restrict__ Wpk, int blk)
{
    const int idx = blk * 256 + threadIdx.x;   // [N/16][K/8][16]
    const int ni  = idx & 15;
    const int kc  = (idx >> 4) % (K / 8);
    const int nt  = idx / (16 * (K / 8));
    const int n   = nt * 16 + ni;
    unsigned short o[8];
#pragma unroll
    for (int i = 0; i < 8; ++i)
        o[i] = f2bf(W[(size_t)(kc * 8 + i) * N + n]);
    *reinterpret_cast<short8*>(Wpk + (size_t)idx * 8) = *reinterpret_cast<short8*>(o);
}

__global__ __launch_bounds__(256) void pack_all_kernel(const float* __restrict__ Wqkv,
                                                       const float* __restrict__ W_in,
                                                       const float* __restrict__ W_out,
                                                       unsigned short* __restrict__ pq,
                                                       unsigned short* __restrict__ pi,
                                                       unsigned short* __restrict__ po)
{
    const int b = blockIdx.x;
    if (b < 96)       pack_body<D, D3 >(Wqkv, pq, b);
    else if (b < 224) pack_body<D, DFF>(W_in, pi, b - 96);
    else              pack_body<DFF, D>(W_out, po, b - 224);
}

// ---------------------------------------------------------------------------
// bf16 MFMA GEMM -- m97 staging structure (round-5 best: 128x128 tile,
// 4 waves, BK=32, global_load_lds width 16, barrier-synced K loop), LDS
// 16 KB, 4 blocks/CU. Panel-colocating XCD swizzle. MFMA operands SWAPPED:
// D maps to row r = lane&15, cols n = (lane>>4)*4+t -> 4 consecutive cols.
// EPI 0: qkv 3-way split -> q fp8 (unscaled), k bf16 [node][256], v fp8
// EPI 1: bf16 C in fragment order [M/16][N/8][16][8] + fast exact gelu
// EPI 2: fp32 C row-major += Xadd, nontemporal f32x4 load/store
// ---------------------------------------------------------------------------
template <int EPI, int K, int N>
__global__ __launch_bounds__(256, 4) void mfma_gemm_kernel(const unsigned short* __restrict__ A,
                                                           const unsigned short* __restrict__ Bpk,
                                                           const float* __restrict__ bias,
                                                           void* __restrict__ Cout,
                                                           void* __restrict__ Cout2,
                                                           void* __restrict__ Cout3,
                                                           const float* __restrict__ Xadd)
{
    constexpr int C = N / 128;           // col tiles
    constexpr int P = M_PAD / 128;       // 313 row panels

    const int bid = blockIdx.x;
    const int xcd = bid & 7;
    const int t   = bid >> 3;
    const int c   = t % C;
    const int p   = (t / C) * 8 + xcd;
    if (p >= P) return;

    __shared__ unsigned short As[4096];   // [mt8][16][8] = 8 KB
    __shared__ unsigned short Bs[4096];

    const int tid  = threadIdx.x;
    const int wave = tid >> 6;
    const int lane = tid & 63;
    const int row0 = p * 128;
    const int col0 = c * 128;
    const int wm   = (wave >> 1) * 64;
    const int wn   = (wave & 1) * 64;
    const int g    = lane >> 4;
    const int q    = lane & 15;

    f32x4 acc[4][4] = {};

    const int fragoff = g * 128 + q * 8;

    for (int k0 = 0; k0 < K; k0 += 32) {
        const int kq = k0 >> 3;   // k-chunk index (K/8 units)
#pragma unroll
        for (int cc = 0; cc < 2; ++cc) {
            const int mt = wave * 2 + cc;                // 0..7
            const unsigned short* gA =
                A + ((size_t)(row0 / 16 + mt) * (K / 8) + kq) * 128 + lane * 8;
            GLOAD_LDS16(gA, &As[mt * 512]);
            const unsigned short* gB =
                Bpk + ((size_t)(col0 / 16 + mt) * (K / 8) + kq) * 128 + lane * 8;
            GLOAD_LDS16(gB, &Bs[mt * 512]);
        }
        __syncthreads();

        short8 af[4], bf[4];
#pragma unroll
        for (int i = 0; i < 4; ++i) {
            af[i] = *reinterpret_cast<const short8*>(&As[(wm / 16 + i) * 512 + fragoff]);
            bf[i] = *reinterpret_cast<const short8*>(&Bs[(wn / 16 + i) * 512 + fragoff]);
        }
#pragma unroll
        for (int i = 0; i < 4; ++i)
#pragma unroll
            for (int j = 0; j < 4; ++j)
                acc[i][j] = __builtin_amdgcn_mfma_f32_16x16x32_bf16(bf[j], af[i], acc[i][j], 0, 0, 0);
        __syncthreads();
    }

    // Swapped D layout: r = row0+wm+i*16+q ; n = col0+wn+j*16+g*4+t (t=0..3)
    if constexpr (EPI == 0) {
        if (col0 < 256) {        // q cols -> fp8, UNSCALED (scale folded into k)
            unsigned char* q8 = (unsigned char*)Cout;
#pragma unroll
            for (int j = 0; j < 4; ++j) {
                const int nb = col0 + wn + j * 16 + g * 4;
                const float4 bz = *reinterpret_cast<const float4*>(bias + nb);
#pragma unroll
                for (int i = 0; i < 4; ++i) {
                    const int r = row0 + wm + i * 16 + q;
                    if (r >= N_NODES) continue;
                    const unsigned int w = pack4_e4m3(acc[i][j][0] + bz.x, acc[i][j][1] + bz.y,
                                                      acc[i][j][2] + bz.z, acc[i][j][3] + bz.w);
                    *reinterpret_cast<unsigned int*>(q8 + (size_t)r * 256 + nb) = w;
                }
            }
        } else if (col0 < 512) { // k cols -> bf16 row-major [node][256]
            unsigned short* kb = (unsigned short*)Cout2;
#pragma unroll
            for (int j = 0; j < 4; ++j) {
                const int nb = col0 + wn + j * 16 + g * 4;
                const float4 bz = *reinterpret_cast<const float4*>(bias + nb);
#pragma unroll
                for (int i = 0; i < 4; ++i) {
                    const int r = row0 + wm + i * 16 + q;
                    if (r >= N_NODES) continue;
                    ushort4 u;
                    u.x = f2bf(acc[i][j][0] + bz.x);
                    u.y = f2bf(acc[i][j][1] + bz.y);
                    u.z = f2bf(acc[i][j][2] + bz.z);
                    u.w = f2bf(acc[i][j][3] + bz.w);
                    *reinterpret_cast<ushort4*>(kb + (size_t)r * 256 + (nb - 256)) = u;
                }
            }
        } else {                 // v cols -> fp8 [node][256]
            unsigned char* v8 = (unsigned char*)Cout3;
#pragma unroll
            for (int j = 0; j < 4; ++j) {
                const int nb = col0 + wn + j * 16 + g * 4;
                const float4 bz = *reinterpret_cast<const float4*>(bias + nb);
#pragma unroll
                for (int i = 0; i < 4; ++i) {
                    const int r = row0 + wm + i * 16 + q;
                    if (r >= N_NODES) continue;
                    const unsigned int w = pack4_e4m3(acc[i][j][0] + bz.x, acc[i][j][1] + bz.y,
                                                      acc[i][j][2] + bz.z, acc[i][j][3] + bz.w);
                    *reinterpret_cast<unsigned int*>(v8 + (size_t)r * 256 + (nb - 512)) = w;
                }
            }
        }
    } else if constexpr (EPI == 1) {
#pragma unroll
        for (int j = 0; j < 4; ++j) {
            const int nb = col0 + wn + j * 16 + g * 4;
            const float4 bz = *reinterpret_cast<const float4*>(bias + nb);
#pragma unroll
            for (int i = 0; i < 4; ++i) {
                const int r = row0 + wm + i * 16 + q;   // pad rows stored too (finite)
                const float o0 = fast_gelu(acc[i][j][0] + bz.x);
                const float o1 = fast_gelu(acc[i][j][1] + bz.y);
                const float o2 = fast_gelu(acc[i][j][2] + bz.z);
                const float o3 = fast_gelu(acc[i][j][3] + bz.w);
                const size_t off = (((size_t)(r >> 4) * (N / 8) + (nb >> 3)) * 16
                                    + (r & 15)) * 8 + (nb & 7);
                ushort4 u;
                u.x = f2bf(o0); u.y = f2bf(o1); u.z = f2bf(o2); u.w = f2bf(o3);
                *reinterpret_cast<ushort4*>((unsigned short*)Cout + off) = u;
            }
        }
    } else {
#pragma unroll
        for (int j = 0; j < 4; ++j) {
            const int nb = col0 + wn + j * 16 + g * 4;
            const float4 bz = *reinterpret_cast<const float4*>(bias + nb);
#pragma unroll
            for (int i = 0; i < 4; ++i) {
                const int r = row0 + wm + i * 16 + q;
                if (r >= N_NODES) continue;
                const f32x4 xd = __builtin_nontemporal_load(
                    reinterpret_cast<const f32x4*>(Xadd + (size_t)r * N + nb));
                f32x4 ov;
                ov[0] = acc[i][j][0] + bz.x + xd[0];
                ov[1] = acc[i][j][1] + bz.y + xd[1];
                ov[2] = acc[i][j][2] + bz.z + xd[2];
                ov[3] = acc[i][j][3] + bz.w + xd[3];
                __builtin_nontemporal_store(ov,
                    reinterpret_cast<f32x4*>((float*)Cout + (size_t)r * N + nb));
            }
        }
    }
}

// ---------------------------------------------------------------------------
// CSR build
// ---------------------------------------------------------------------------
__global__ __launch_bounds__(256) void hist_kernel(const int* __restrict__ dst,
                                                   int* __restrict__ counts)
{
    const int i = blockIdx.x * 256 + threadIdx.x;
    atomicAdd(&counts[dst[i]], 1);
}

// Two-pass, ARRAY-FREE scan: the old int c[40] per-thread array spilled to
// scratch (VGPR_Count=24 < 40) -> 64 us on one CU. Phase 1 sums via int4
// loads (consumed immediately, no storage); phase 2 re-reads (L1-warm) and
// writes rowptr+cursor as int4. 1000 active threads x exactly 40 elements.
__global__ __launch_bounds__(1024) void scan_kernel(const int* __restrict__ counts,
                                                    int* __restrict__ rowptr,
                                                    int* __restrict__ cursor)
{
    const int PER = 40;
    const int tid  = threadIdx.x;
    const int base = tid * PER;
    const bool act = (base < N_NODES);     // threads 0..999 own 40 each
    int s = 0;
    if (act) {
#pragma unroll
        for (int i = 0; i < PER / 4; ++i) {
            const int4 c4 = *reinterpret_cast<const int4*>(counts + base + i * 4);
            s += (c4.x + c4.y) + (c4.z + c4.w);
        }
    }
    __shared__ int sm[1024];
    sm[tid] = s;
    __syncthreads();
    for (int off = 1; off < 1024; off <<= 1) {
        int t = (tid >= off) ? sm[tid - off] : 0;
        __syncthreads();
        sm[tid] += t;
        __syncthreads();
    }
    int run = sm[tid] - s;                 // exclusive prefix of this chunk
    if (act) {
#pragma unroll
        for (int i = 0; i < PER / 4; ++i) {
            const int4 c4 = *reinterpret_cast<const int4*>(counts + base + i * 4);
            int4 r4;
            r4.x = run;
            r4.y = r4.x + c4.x;
            r4.z = r4.y + c4.y;
            r4.w = r4.z + c4.z;
            run  = r4.w + c4.w;
            *reinterpret_cast<int4*>(rowptr + base + i * 4) = r4;
            *reinterpret_cast<int4*>(cursor + base + i * 4) = r4;
        }
    }
    if (tid == 1023) rowptr[N_NODES] = sm[1023];
}

__global__ __launch_bounds__(256) void fill_kernel(const int* __restrict__ src,
                                                   const int* __restrict__ dst,
                                                   int* __restrict__ cursor,
                                                   int* __restrict__ srcs)
{
    const int e = blockIdx.x * 256 + threadIdx.x;
    const int pos = atomicAdd(&cursor[dst[e]], 1);
    if (pos >= 0 && pos < N_EDGES) srcs[pos] = src[e];
}

// ---------------------------------------------------------------------------
// Fused attention: q fp8 (256 B/row, gathered) + v fp8 (256 B/row, gathered)
// + k bf16 (512 B/row, loaded once per dst node). Edge gather = 512 B.
// One wave per dst node; src list coalesce-prefetched, readlane broadcast,
// 4-edge unroll. k scaled by ATT_SCALE at load.
// Outputs: x fp32 row-major, xn bf16 in fragment order.
// ---------------------------------------------------------------------------
__global__ __launch_bounds__(256) void fused_attn_kernel(const unsigned char* __restrict__ qf8,
                                                         const unsigned short* __restrict__ kbf,
                                                         const unsigned char* __restrict__ vf8,
                                                         const int* __restrict__ srcs,
                                                         const int* __restrict__ rowptr,
                                                         const float* __restrict__ triplet_h,
                                                         const float* __restrict__ g,
                                                         const float* __restrict__ b,
                                                         float* __restrict__ x,
                                                         unsigned short* __restrict__ xn)
{
    const int node = blockIdx.x * 4 + (threadIdx.x >> 6);
    const int lane = threadIdx.x & 63;
    int beg = rowptr[node];
    int end = rowptr[node + 1];
    beg = max(0, min(beg, N_EDGES));
    end = max(beg, min(end, N_EDGES));
    const int deg = end - beg;

    const ushort4 ku = *reinterpret_cast<const ushort4*>(
        kbf + (size_t)node * 256 + lane * 4);
    const float k0 = bf2f(ku.x) * ATT_SCALE, k1 = bf2f(ku.y) * ATT_SCALE;
    const float k2 = bf2f(ku.z) * ATT_SCALE, k3 = bf2f(ku.w) * ATT_SCALE;

    float dsum = 0.0f;
    float4 acc = {0.0f, 0.0f, 0.0f, 0.0f};

    for (int base = 0; base < deg; base += 64) {
        const int cnt = min(64, deg - base);
        const int idx = base + lane;
        const int sv = (idx < deg) ? srcs[beg + idx] : 0;   // coalesced prefetch
        int j = 0;
        for (; j + 4 <= cnt; j += 4) {
            const int s0 = __builtin_amdgcn_readlane(sv, j);
            const int s1 = __builtin_amdgcn_readlane(sv, j + 1);
            const int s2 = __builtin_amdgcn_readlane(sv, j + 2);
            const int s3 = __builtin_amdgcn_readlane(sv, j + 3);
            const unsigned int qa = *reinterpret_cast<const unsigned int*>(qf8 + (size_t)s0 * 256 + lane * 4);
            const unsigned int qb = *reinterpret_cast<const unsigned int*>(qf8 + (size_t)s1 * 256 + lane * 4);
            const unsigned int qc = *reinterpret_cast<const unsigned int*>(qf8 + (size_t)s2 * 256 + lane * 4);
            const unsigned int qd = *reinterpret_cast<const unsigned int*>(qf8 + (size_t)s3 * 256 + lane * 4);
            const unsigned int va = *reinterpret_cast<const unsigned int*>(vf8 + (size_t)s0 * 256 + lane * 4);
            const unsigned int vb = *reinterpret_cast<const unsigned int*>(vf8 + (size_t)s1 * 256 + lane * 4);
            const unsigned int vc = *reinterpret_cast<const unsigned int*>(vf8 + (size_t)s2 * 256 + lane * 4);
            const unsigned int vd = *reinterpret_cast<const unsigned int*>(vf8 + (size_t)s3 * 256 + lane * 4);
            float a0, a1, a2, a3;
            dec4_e4m3(qa, a0, a1, a2, a3);
            float p0 = a0 * k0 + a1 * k1 + a2 * k2 + a3 * k3;
            dec4_e4m3(qb, a0, a1, a2, a3);
            float p1 = a0 * k0 + a1 * k1 + a2 * k2 + a3 * k3;
            dec4_e4m3(qc, a0, a1, a2, a3);
            float p2 = a0 * k0 + a1 * k1 + a2 * k2 + a3 * k3;
            dec4_e4m3(qd, a0, a1, a2, a3);
            float p3 = a0 * k0 + a1 * k1 + a2 * k2 + a3 * k3;
            p0 += __shfl_xor(p0, 1, 64); p1 += __shfl_xor(p1, 1, 64);
            p2 += __shfl_xor(p2, 1, 64); p3 += __shfl_xor(p3, 1, 64);
            p0 += __shfl_xor(p0, 2, 64); p1 += __shfl_xor(p1, 2, 64);
            p2 += __shfl_xor(p2, 2, 64); p3 += __shfl_xor(p3, 2, 64);
            p0 += __shfl_xor(p0, 4, 64); p1 += __shfl_xor(p1, 4, 64);
            p2 += __shfl_xor(p2, 4, 64); p3 += __shfl_xor(p3, 4, 64);
            const float w0 = __expf(p0), w1 = __expf(p1), w2 = __expf(p2), w3 = __expf(p3);
            float v0, v1, v2, v3;
            dec4_e4m3(va, v0, v1, v2, v3);
            acc.x += w0 * v0; acc.y += w0 * v1; acc.z += w0 * v2; acc.w += w0 * v3;
            dec4_e4m3(vb, v0, v1, v2, v3);
            acc.x += w1 * v0; acc.y += w1 * v1; acc.z += w1 * v2; acc.w += w1 * v3;
            dec4_e4m3(vc, v0, v1, v2, v3);
            acc.x += w2 * v0; acc.y += w2 * v1; acc.z += w2 * v2; acc.w += w2 * v3;
            dec4_e4m3(vd, v0, v1, v2, v3);
            acc.x += w3 * v0; acc.y += w3 * v1; acc.z += w3 * v2; acc.w += w3 * v3;
            dsum += (w0 + w1) + (w2 + w3);
        }
        for (; j < cnt; ++j) {
            const int s0 = __builtin_amdgcn_readlane(sv, j);
            const unsigned int qa = *reinterpret_cast<const unsigned int*>(qf8 + (size_t)s0 * 256 + lane * 4);
            const unsigned int va = *reinterpret_cast<const unsigned int*>(vf8 + (size_t)s0 * 256 + lane * 4);
            float a0, a1, a2, a3;
            dec4_e4m3(qa, a0, a1, a2, a3);
            float p0 = a0 * k0 + a1 * k1 + a2 * k2 + a3 * k3;
            p0 += __shfl_xor(p0, 1, 64);
            p0 += __shfl_xor(p0, 2, 64);
            p0 += __shfl_xor(p0, 4, 64);
            const float w0 = __expf(p0);
            float v0, v1, v2, v3;
            dec4_e4m3(va, v0, v1, v2, v3);
            acc.x += w0 * v0; acc.y += w0 * v1; acc.z += w0 * v2; acc.w += w0 * v3;
            dsum += w0;
        }
    }
    const float inv = (deg > 0) ? 1.0f / dsum : 0.0f;

    const float4 th = *reinterpret_cast<const float4*>(
        triplet_h + (size_t)node * D + lane * 4);
    float4 xv;
    xv.x = th.x + acc.x * inv;
    xv.y = th.y + acc.y * inv;
    xv.z = th.z + acc.z * inv;
    xv.w = th.w + acc.w * inv;
    *reinterpret_cast<float4*>(x + (size_t)node * D + lane * 4) = xv;

    // LN2 across the wave
    float s  = xv.x + xv.y + xv.z + xv.w;
    float s2 = xv.x * xv.x + xv.y * xv.y + xv.z * xv.z + xv.w * xv.w;
#pragma unroll
    for (int o = 32; o > 0; o >>= 1) {
        s  += __shfl_xor(s,  o, 64);
        s2 += __shfl_xor(s2, o, 64);
    }
    const float mu  = s * (1.0f / D);
    const float var = s2 * (1.0f / D) - mu * mu;
    const float rs  = rsqrtf(var + LN_EPS);
    const float4 gg = *reinterpret_cast<const float4*>(g + lane * 4);
    const float4 bb = *reinterpret_cast<const float4*>(b + lane * 4);
    ushort4 o4;
    o4.x = f2bf((xv.x - mu) * rs * gg.x + bb.x);
    o4.y = f2bf((xv.y - mu) * rs * gg.y + bb.y);
    o4.z = f2bf((xv.z - mu) * rs * gg.z + bb.z);
    o4.w = f2bf((xv.w - mu) * rs * gg.w + bb.w);
    const size_t off = (((size_t)(node >> 4) * (D / 8) + (lane >> 1)) * 16 + (node & 15)) * 8
                       + (lane & 1) * 4;
    *reinterpret_cast<ushort4*>(xn + off) = o4;
}

// ---------------------------------------------------------------------------
extern "C" void kernel_launch(void* const* d_in, const int* in_sizes, int n_in,
                              void* d_out, int out_size, void* d_ws, size_t ws_size,
                              hipStream_t stream)
{
    const float* triplet_h = (const float*)d_in[0];
    const int*   src       = (const int*)d_in[1];
    const int*   dst       = (const int*)d_in[2];
    const float* Wqkv      = (const float*)d_in[3];
    const float* bqkv      = (const float*)d_in[4];
    const float* ln_attn_g = (const float*)d_in[5];
    const float* ln_attn_b = (const float*)d_in[6];
    const float* ln_res_g  = (const float*)d_in[7];
    const float* ln_res_b  = (const float*)d_in[8];
    const float* W_in      = (const float*)d_in[9];
    const float* b_in      = (const float*)d_in[10];
    const float* W_out     = (const float*)d_in[11];
    const float* b_out     = (const float*)d_in[12];
    float* out = (float*)d_out;

    // Workspace (~175 MB, under 245.76 MB ceiling):
    char* w = (char*)d_ws;
    unsigned short* bufA = (unsigned short*)w;   // kbf (EPI0 out) OR a1 bf16 frag
    w += (size_t)M_PAD * DFF * sizeof(unsigned short);
    unsigned short* h_xn = (unsigned short*)w;  w += (size_t)M_PAD * D * sizeof(unsigned short);
    float*          x    = (float*)w;           w += (size_t)N_NODES * D * sizeof(float);
    unsigned char*  qf8  = (unsigned char*)w;   w += (size_t)N_NODES * 256;
    unsigned char*  vf8  = (unsigned char*)w;   w += (size_t)N_NODES * 256;
    unsigned short* Wqkv_pk = (unsigned short*)w; w += (size_t)D * D3 * sizeof(unsigned short);
    unsigned short* Win_pk  = (unsigned short*)w; w += (size_t)D * DFF * sizeof(unsigned short);
    unsigned short* Wout_pk = (unsigned short*)w; w += (size_t)DFF * D * sizeof(unsigned short);
    int* counts = (int*)w;  w += (size_t)N_NODES * sizeof(int);
    int* rowptr = (int*)w;  w += (size_t)(N_NODES + 1) * sizeof(int);
    int* cursor = (int*)w;  w += (size_t)N_NODES * sizeof(int);
    int* srcs   = (int*)w;  w += (size_t)N_EDGES * sizeof(int);

    unsigned short* kbf = bufA;  // [40000][256] bf16 (k), dead after fused_attn
    unsigned short* a1  = bufA;  // [M_PAD/16][128][16][8] bf16 frag, live FFN only

    // ---- CSR build ----
    (void)hipMemsetAsync(counts, 0, (size_t)N_NODES * sizeof(int), stream);
    hist_kernel<<<N_EDGES / 256, 256, 0, stream>>>(dst, counts);
    scan_kernel<<<1, 1024, 0, stream>>>(counts, rowptr, cursor);
    fill_kernel<<<N_EDGES / 256, 256, 0, stream>>>(src, dst, cursor, srcs);

    // ---- weight packing (one launch) ----
    pack_all_kernel<<<352, 256, 0, stream>>>(Wqkv, W_in, W_out, Wqkv_pk, Win_pk, Wout_pk);

    // ---- main pipeline ----
    ln_bf_kernel<<<M_PAD / 4, 256, 0, stream>>>(triplet_h, ln_attn_g, ln_attn_b, h_xn);
    mfma_gemm_kernel<0, D, D3><<<((M_PAD / 128 + 7) / 8) * 8 * (D3 / 128), 256, 0, stream>>>(
        h_xn, Wqkv_pk, bqkv, qf8, kbf, vf8, nullptr);
    fused_attn_kernel<<<N_NODES / 4, 256, 0, stream>>>(qf8, kbf, vf8, srcs, rowptr, triplet_h,
                                                       ln_res_g, ln_res_b, x, h_xn);
    // kbf dead; a1 overwrites it (EPI1 stores pad rows too -> no memset needed)
    mfma_gemm_kernel<1, D, DFF><<<((M_PAD / 128 + 7) / 8) * 8 * (DFF / 128), 256, 0, stream>>>(
        h_xn, Win_pk, b_in, a1, nullptr, nullptr, nullptr);
    mfma_gemm_kernel<2, DFF, D><<<((M_PAD / 128 + 7) / 8) * 8 * (D / 128), 256, 0, stream>>>(
        a1, Wout_pk, b_out, out, nullptr, nullptr, x);

    (void)in_sizes; (void)n_in; (void)out_size; (void)ws_size;
}